// Round 1
// baseline (1883.591 us; speedup 1.0000x reference)
//
#include <hip/hip_runtime.h>
#include <hip/hip_bf16.h>
#include <math.h>

#define T_SEQ 512
#define BATCH 64
#define DIN   128
#define H     160
#define G3    480   // 3*H

__device__ __forceinline__ float sigmoidf_(float x) {
    return 1.0f / (1.0f + __expf(-x));
}
__device__ __forceinline__ float tanhf_(float x) {
    float a = fabsf(x);
    float e = __expf(2.0f * a);
    float t = 1.0f - 2.0f / (e + 1.0f);
    return copysignf(t, x);
}

// ---------------- block reductions (512 threads = 8 waves) ----------------
__device__ __forceinline__ float blockReduceSum(float v, float* red) {
    #pragma unroll
    for (int off = 32; off > 0; off >>= 1) v += __shfl_down(v, off, 64);
    int wave = threadIdx.x >> 6, lane = threadIdx.x & 63;
    __syncthreads();                 // protect red from previous use
    if (lane == 0) red[wave] = v;
    __syncthreads();
    float s = red[0];
    int nw = blockDim.x >> 6;
    for (int i = 1; i < nw; ++i) s += red[i];
    return s;
}
__device__ __forceinline__ float blockReduceMax(float v, float* red) {
    #pragma unroll
    for (int off = 32; off > 0; off >>= 1) v = fmaxf(v, __shfl_down(v, off, 64));
    int wave = threadIdx.x >> 6, lane = threadIdx.x & 63;
    __syncthreads();
    if (lane == 0) red[wave] = v;
    __syncthreads();
    float s = red[0];
    int nw = blockDim.x >> 6;
    for (int i = 1; i < nw; ++i) s = fmaxf(s, red[i]);
    return s;
}

// ---------------- tiled fp32 GEMM: C[M,N] = A[M,K] * B[N,K]^T + bias, opt tanh ----
__global__ __launch_bounds__(256) void gemm_bias_kernel(
    const float* __restrict__ A, const float* __restrict__ B,
    const float* __restrict__ bias, float* __restrict__ C,
    int M, int N, int K, int act)
{
    const int BM = 64, BN = 64, BK = 32;
    __shared__ __align__(16) float As[BK][BM];   // k-major
    __shared__ __align__(16) float Bs[BK][BN];
    int tid  = threadIdx.x;
    int row0 = blockIdx.x * BM;
    int col0 = blockIdx.y * BN;
    int tx = tid & 15, ty = tid >> 4;
    float acc[4][4] = {};

    for (int k0 = 0; k0 < K; k0 += BK) {
        #pragma unroll
        for (int v = 0; v < 2; ++v) {
            int idx = tid + v * 256;       // 0..511 over 64 rows x 8 vec4
            int m   = idx >> 3;
            int kq  = (idx & 7) << 2;
            float4 a4 = *reinterpret_cast<const float4*>(A + (size_t)(row0 + m) * K + k0 + kq);
            As[kq + 0][m] = a4.x; As[kq + 1][m] = a4.y;
            As[kq + 2][m] = a4.z; As[kq + 3][m] = a4.w;
            float4 b4 = make_float4(0.f, 0.f, 0.f, 0.f);
            if (col0 + m < N)
                b4 = *reinterpret_cast<const float4*>(B + (size_t)(col0 + m) * K + k0 + kq);
            Bs[kq + 0][m] = b4.x; Bs[kq + 1][m] = b4.y;
            Bs[kq + 2][m] = b4.z; Bs[kq + 3][m] = b4.w;
        }
        __syncthreads();
        #pragma unroll
        for (int kk = 0; kk < BK; ++kk) {
            float4 a4 = *reinterpret_cast<const float4*>(&As[kk][ty << 2]);
            float4 b4 = *reinterpret_cast<const float4*>(&Bs[kk][tx << 2]);
            float av[4] = {a4.x, a4.y, a4.z, a4.w};
            float bv[4] = {b4.x, b4.y, b4.z, b4.w};
            #pragma unroll
            for (int i = 0; i < 4; ++i)
                #pragma unroll
                for (int j = 0; j < 4; ++j) acc[i][j] += av[i] * bv[j];
        }
        __syncthreads();
    }
    #pragma unroll
    for (int i = 0; i < 4; ++i) {
        int row = row0 + (ty << 2) + i;
        #pragma unroll
        for (int j = 0; j < 4; ++j) {
            int col = col0 + (tx << 2) + j;
            if (col < N) {
                float v = acc[i][j] + bias[col];
                if (act == 1) v = tanhf_(v);
                C[(size_t)row * N + col] = v;
            }
        }
    }
}

// ---------------- GRU recurrence: one block per (batch, dir) ----------------
// xw: [B][T][960] (dir0: 0..479, dir1: 480..959), whh: [2][480][160],
// bhh: [2][480], out: [B][T][320] (dir0 -> 0..159, dir1 -> 160..319)
__global__ __launch_bounds__(512) void gru_kernel(
    const float* __restrict__ xw, const float* __restrict__ whh,
    const float* __restrict__ bhh, float* __restrict__ out)
{
    int b   = blockIdx.x >> 1;
    int dir = blockIdx.x & 1;
    int r   = threadIdx.x;
    __shared__ __align__(16) float h_s[H];
    __shared__ float g_s[G3];
    float w[H];
    float bias = 0.f;
    if (r < G3) {
        const float* wp = whh + (size_t)dir * G3 * H + (size_t)r * H;
        #pragma unroll
        for (int k = 0; k < H; k += 4) {
            float4 v = *reinterpret_cast<const float4*>(wp + k);
            w[k] = v.x; w[k + 1] = v.y; w[k + 2] = v.z; w[k + 3] = v.w;
        }
        bias = bhh[dir * G3 + r];
    }
    if (r < H) h_s[r] = 0.f;
    __syncthreads();

    for (int step = 0; step < T_SEQ; ++step) {
        int tt = dir ? (T_SEQ - 1 - step) : step;
        size_t base = ((size_t)b * T_SEQ + tt) * 960 + (size_t)dir * G3;
        float xr = 0.f, xz = 0.f, xn = 0.f;
        if (r < H) {   // issue early; independent of the dot below
            xr = xw[base + r];
            xz = xw[base + H + r];
            xn = xw[base + 2 * H + r];
        }
        if (r < G3) {
            float acc = bias;
            #pragma unroll
            for (int k = 0; k < H; k += 4) {
                float4 h4 = *reinterpret_cast<const float4*>(&h_s[k]);
                acc += h4.x * w[k] + h4.y * w[k + 1] + h4.z * w[k + 2] + h4.w * w[k + 3];
            }
            g_s[r] = acc;
        }
        __syncthreads();
        if (r < H) {
            float rg = sigmoidf_(xr + g_s[r]);
            float z  = sigmoidf_(xz + g_s[H + r]);
            float n  = tanhf_(xn + rg * g_s[2 * H + r]);
            float hn = (1.0f - z) * n + z * h_s[r];
            h_s[r] = hn;
            out[((size_t)b * T_SEQ + tt) * 320 + (size_t)dir * H + r] = hn;
        }
        __syncthreads();
    }
}

// ---------------- attn logits: [32768][4] = keys[tok][160] . score_w[h][160] + b ---
__global__ __launch_bounds__(256) void logits_kernel(
    const float* __restrict__ keys, const float* __restrict__ sw,
    const float* __restrict__ sb, float* __restrict__ out)
{
    int gid = blockIdx.x * 256 + threadIdx.x;
    int tok = gid >> 2, h = gid & 3;
    const float4* kr = reinterpret_cast<const float4*>(keys + (size_t)tok * H);
    const float4* wr = reinterpret_cast<const float4*>(sw + (size_t)h * H);
    float acc = 0.f;
    #pragma unroll
    for (int i = 0; i < H / 4; ++i) {
        float4 a = kr[i], w4 = wr[i];
        acc += a.x * w4.x + a.y * w4.y + a.z * w4.z + a.w * w4.w;
    }
    out[gid] = acc + sb[h];
}

// ---------------- epilogue: motion + softmax + pool + proj + LN + L2, 1 block/batch --
__global__ __launch_bounds__(512) void final_kernel(
    const float* __restrict__ x, const float* __restrict__ logits,
    const float* __restrict__ seq, const float* __restrict__ proj_w,
    const float* __restrict__ proj_b, const float* __restrict__ ln_g,
    const float* __restrict__ ln_b, float* __restrict__ out)
{
    int b   = blockIdx.x;
    int tid = threadIdx.x;
    __shared__ float ms[T_SEQ];
    __shared__ float ss[T_SEQ];
    __shared__ __align__(16) float pooled[320];
    __shared__ float red[8];

    // Phase A: motion[t] = ||x[t]-x[t-1]||, m[0]=m[1]; standardize (ddof=1)
    {
        float m = 0.f;
        if (tid >= 1) {
            const float4* xc = reinterpret_cast<const float4*>(x + ((size_t)b * T_SEQ + tid) * DIN);
            const float4* xp = reinterpret_cast<const float4*>(x + ((size_t)b * T_SEQ + tid - 1) * DIN);
            float s = 0.f;
            #pragma unroll
            for (int i = 0; i < DIN / 4; ++i) {
                float4 a = xc[i], p = xp[i];
                float dx = a.x - p.x, dy = a.y - p.y, dz = a.z - p.z, dw = a.w - p.w;
                s += dx * dx + dy * dy + dz * dz + dw * dw;
            }
            m = sqrtf(s);
        }
        ms[tid] = m;
    }
    __syncthreads();
    if (tid == 0) ms[0] = ms[1];
    __syncthreads();
    float mv   = ms[tid];
    float mean = blockReduceSum(mv, red) * (1.0f / T_SEQ);
    float var  = blockReduceSum((mv - mean) * (mv - mean), red) * (1.0f / (T_SEQ - 1));
    float mstd = (mv - mean) / (sqrtf(var) + 1e-6f);

    // Phase B: 4 softmaxes over t; s[t] = mean_h weights
    float4 lg = *reinterpret_cast<const float4*>(logits + ((size_t)b * T_SEQ + tid) * 4);
    float l[4] = {lg.x + mstd, lg.y + mstd, lg.z + mstd, lg.w + mstd};
    float ssum = 0.f;
    #pragma unroll
    for (int h = 0; h < 4; ++h) {
        float mx = blockReduceMax(l[h], red);
        float e  = __expf(l[h] - mx);
        float se = blockReduceSum(e, red);
        float wv = e / se;
        ssum += wv;
    }
    float sv = ssum * 0.25f;
    ss[tid] = sv;
    out[16384 + b * T_SEQ + tid] = sv;   // output 1: weights.mean(axis=2)
    __syncthreads();

    // Phase C: pooled[d] = sum_t seq[b,t,d] * s[t]
    if (tid < 320) {
        float acc = 0.f;
        const float* sp = seq + (size_t)b * T_SEQ * 320 + tid;
        #pragma unroll 4
        for (int t = 0; t < T_SEQ; ++t) acc += sp[(size_t)t * 320] * ss[t];
        pooled[tid] = acc;
    }
    __syncthreads();

    // Phase D: embedding = pooled . proj_w^T + b ; LN ; L2-normalize
    float e = 0.f;
    if (tid < 256) {
        const float4* pw = reinterpret_cast<const float4*>(proj_w + (size_t)tid * 320);
        const float4* pl = reinterpret_cast<const float4*>(pooled);
        float acc = 0.f;
        #pragma unroll
        for (int i = 0; i < 80; ++i) {
            float4 w4 = pw[i], p4 = pl[i];
            acc += w4.x * p4.x + w4.y * p4.y + w4.z * p4.z + w4.w * p4.w;
        }
        e = acc + proj_b[tid];
    }
    float mu = blockReduceSum(tid < 256 ? e : 0.f, red) * (1.0f / 256);
    float dv = (tid < 256) ? (e - mu) : 0.f;
    float vr = blockReduceSum(dv * dv, red) * (1.0f / 256);
    float g  = 0.f;
    if (tid < 256) g = (e - mu) * rsqrtf(vr + 1e-5f) * ln_g[tid] + ln_b[tid];
    float nrm = sqrtf(blockReduceSum(g * g, red));
    nrm = fmaxf(nrm, 1e-12f);
    if (tid < 256) out[b * 256 + tid] = g / nrm;
}

extern "C" void kernel_launch(void* const* d_in, const int* in_sizes, int n_in,
                              void* d_out, int out_size, void* d_ws, size_t ws_size,
                              hipStream_t stream) {
    const float* x       = (const float*)d_in[0];
    const float* Wih0    = (const float*)d_in[1];
    const float* Whh0    = (const float*)d_in[2];
    const float* bih0    = (const float*)d_in[3];
    const float* bhh0    = (const float*)d_in[4];
    const float* Wih1    = (const float*)d_in[5];
    const float* Whh1    = (const float*)d_in[6];
    const float* bih1    = (const float*)d_in[7];
    const float* bhh1    = (const float*)d_in[8];
    const float* key_w   = (const float*)d_in[9];
    const float* key_b   = (const float*)d_in[10];
    const float* score_w = (const float*)d_in[11];
    const float* score_b = (const float*)d_in[12];
    const float* proj_w  = (const float*)d_in[13];
    const float* proj_b  = (const float*)d_in[14];
    const float* ln_g    = (const float*)d_in[15];
    const float* ln_b    = (const float*)d_in[16];

    float* ws    = (float*)d_ws;
    float* xwbuf = ws;                        // 32768*960  = 31457280 (reused for xw1)
    float* h1    = ws + 31457280;             // 32768*320  = 10485760
    float* seq   = h1 + 10485760;             // 32768*320  = 10485760
    float* keys  = seq + 10485760;            // 32768*160  =  5242880
    float* lgts  = keys + 5242880;            // 32768*4    =   131072
    float* outf  = (float*)d_out;

    const int M = BATCH * T_SEQ;              // 32768

    gemm_bias_kernel<<<dim3(M / 64, 15), 256, 0, stream>>>(x,   Wih0, bih0, xwbuf, M, 960, 128, 0);
    gru_kernel<<<128, 512, 0, stream>>>(xwbuf, Whh0, bhh0, h1);
    gemm_bias_kernel<<<dim3(M / 64, 15), 256, 0, stream>>>(h1,  Wih1, bih1, xwbuf, M, 960, 320, 0);
    gru_kernel<<<128, 512, 0, stream>>>(xwbuf, Whh1, bhh1, seq);
    gemm_bias_kernel<<<dim3(M / 64, 3),  256, 0, stream>>>(seq, key_w, key_b, keys, M, 160, 320, 1);
    logits_kernel<<<512, 256, 0, stream>>>(keys, score_w, score_b, lgts);
    final_kernel<<<64, 512, 0, stream>>>(x, lgts, seq, proj_w, proj_b, ln_g, ln_b, outf);
}

// Round 2
// 1752.090 us; speedup vs baseline: 1.0751x; 1.0751x over previous
//
#include <hip/hip_runtime.h>
#include <hip/hip_bf16.h>
#include <math.h>

#define T_SEQ 512
#define BATCH 64
#define DIN   128
#define H     160
#define G3    480   // 3*H

__device__ __forceinline__ float sigmoidf_(float x) {
    return 1.0f / (1.0f + __expf(-x));
}
__device__ __forceinline__ float tanhf_(float x) {
    float a = fabsf(x);
    float e = __expf(2.0f * a);
    float t = 1.0f - 2.0f / (e + 1.0f);
    return copysignf(t, x);
}

// ---------------- block reductions (512 threads = 8 waves) ----------------
__device__ __forceinline__ float blockReduceSum(float v, float* red) {
    #pragma unroll
    for (int off = 32; off > 0; off >>= 1) v += __shfl_down(v, off, 64);
    int wave = threadIdx.x >> 6, lane = threadIdx.x & 63;
    __syncthreads();                 // protect red from previous use
    if (lane == 0) red[wave] = v;
    __syncthreads();
    float s = red[0];
    int nw = blockDim.x >> 6;
    for (int i = 1; i < nw; ++i) s += red[i];
    return s;
}
__device__ __forceinline__ float blockReduceMax(float v, float* red) {
    #pragma unroll
    for (int off = 32; off > 0; off >>= 1) v = fmaxf(v, __shfl_down(v, off, 64));
    int wave = threadIdx.x >> 6, lane = threadIdx.x & 63;
    __syncthreads();
    if (lane == 0) red[wave] = v;
    __syncthreads();
    float s = red[0];
    int nw = blockDim.x >> 6;
    for (int i = 1; i < nw; ++i) s = fmaxf(s, red[i]);
    return s;
}

// ---------------- tiled fp32 GEMM: C[M,N] = A[M,K] * B[N,K]^T + bias, opt tanh ----
__global__ __launch_bounds__(256) void gemm_bias_kernel(
    const float* __restrict__ A, const float* __restrict__ B,
    const float* __restrict__ bias, float* __restrict__ C,
    int M, int N, int K, int act)
{
    const int BM = 64, BN = 64, BK = 32;
    __shared__ __align__(16) float As[BK][BM];   // k-major
    __shared__ __align__(16) float Bs[BK][BN];
    int tid  = threadIdx.x;
    int row0 = blockIdx.x * BM;
    int col0 = blockIdx.y * BN;
    int tx = tid & 15, ty = tid >> 4;
    float acc[4][4] = {};

    for (int k0 = 0; k0 < K; k0 += BK) {
        #pragma unroll
        for (int v = 0; v < 2; ++v) {
            int idx = tid + v * 256;       // 0..511 over 64 rows x 8 vec4
            int m   = idx >> 3;
            int kq  = (idx & 7) << 2;
            float4 a4 = *reinterpret_cast<const float4*>(A + (size_t)(row0 + m) * K + k0 + kq);
            As[kq + 0][m] = a4.x; As[kq + 1][m] = a4.y;
            As[kq + 2][m] = a4.z; As[kq + 3][m] = a4.w;
            float4 b4 = make_float4(0.f, 0.f, 0.f, 0.f);
            if (col0 + m < N)
                b4 = *reinterpret_cast<const float4*>(B + (size_t)(col0 + m) * K + k0 + kq);
            Bs[kq + 0][m] = b4.x; Bs[kq + 1][m] = b4.y;
            Bs[kq + 2][m] = b4.z; Bs[kq + 3][m] = b4.w;
        }
        __syncthreads();
        #pragma unroll
        for (int kk = 0; kk < BK; ++kk) {
            float4 a4 = *reinterpret_cast<const float4*>(&As[kk][ty << 2]);
            float4 b4 = *reinterpret_cast<const float4*>(&Bs[kk][tx << 2]);
            float av[4] = {a4.x, a4.y, a4.z, a4.w};
            float bv[4] = {b4.x, b4.y, b4.z, b4.w};
            #pragma unroll
            for (int i = 0; i < 4; ++i)
                #pragma unroll
                for (int j = 0; j < 4; ++j) acc[i][j] += av[i] * bv[j];
        }
        __syncthreads();
    }
    #pragma unroll
    for (int i = 0; i < 4; ++i) {
        int row = row0 + (ty << 2) + i;
        #pragma unroll
        for (int j = 0; j < 4; ++j) {
            int col = col0 + (tx << 2) + j;
            if (col < N) {
                float v = acc[i][j] + bias[col];
                if (act == 1) v = tanhf_(v);
                C[(size_t)row * N + col] = v;
            }
        }
    }
}

// ---------------- GRU recurrence: one block per (batch, dir) ----------------
// 1024 threads. Threads 0..959: dot-product workers, thread = (row r = tid>>1,
// K-half = tid&1). Each owns 80 weights in VGPRs (no spill at ~110 VGPRs,
// vs the 160-float array that spilled at VGPR_Count=96 in round 1).
// Partner lanes (tid^1, same wave) combine via __shfl_xor.
// xw: [B][T][960] (dir0: 0..479, dir1: 480..959), whh: [2][480][160],
// bhh: [2][480], out: [B][T][320] (dir0 -> 0..159, dir1 -> 160..319)
__global__ __launch_bounds__(1024) void gru_kernel(
    const float* __restrict__ xw, const float* __restrict__ whh,
    const float* __restrict__ bhh, float* __restrict__ out)
{
    int b    = blockIdx.x >> 1;
    int dir  = blockIdx.x & 1;
    int tid  = threadIdx.x;
    int r    = tid >> 1;
    int half = tid & 1;
    bool active = (tid < 2 * G3);
    __shared__ __align__(16) float h_s[H];
    __shared__ float g_s[G3];

    float w[80];
    float bias = 0.f;
    if (active) {
        const float* wp = whh + (size_t)dir * G3 * H + (size_t)r * H + half * 80;
        #pragma unroll
        for (int k = 0; k < 80; k += 4) {
            float4 v = *reinterpret_cast<const float4*>(wp + k);
            w[k] = v.x; w[k + 1] = v.y; w[k + 2] = v.z; w[k + 3] = v.w;
        }
        bias = bhh[dir * G3 + r];
    }
    if (tid < H) h_s[tid] = 0.f;
    __syncthreads();

    for (int step = 0; step < T_SEQ; ++step) {
        int tt = dir ? (T_SEQ - 1 - step) : step;
        size_t base = ((size_t)b * T_SEQ + tt) * 960 + (size_t)dir * G3;
        float xr = 0.f, xz = 0.f, xn = 0.f;
        if (tid < H) {   // issue early; latency overlaps the dot below
            xr = xw[base + tid];
            xz = xw[base + H + tid];
            xn = xw[base + 2 * H + tid];
        }
        // 80-MAC dot with 4-way ILP accumulators; LDS reads are 2-address
        // broadcast (even lanes h_s[4i..], odd lanes h_s[80+4i..]) -> conflict-free
        float acc0 = 0.f, acc1 = 0.f, acc2 = 0.f, acc3 = 0.f;
        {
            const float* hp = h_s + half * 80;
            #pragma unroll
            for (int i = 0; i < 20; i += 4) {
                float4 ha = *reinterpret_cast<const float4*>(hp + 4 * i);
                float4 hb = *reinterpret_cast<const float4*>(hp + 4 * i + 4);
                float4 hc = *reinterpret_cast<const float4*>(hp + 4 * i + 8);
                float4 hd = *reinterpret_cast<const float4*>(hp + 4 * i + 12);
                acc0 += ha.x * w[4*i+ 0] + ha.y * w[4*i+ 1] + ha.z * w[4*i+ 2] + ha.w * w[4*i+ 3];
                acc1 += hb.x * w[4*i+ 4] + hb.y * w[4*i+ 5] + hb.z * w[4*i+ 6] + hb.w * w[4*i+ 7];
                acc2 += hc.x * w[4*i+ 8] + hc.y * w[4*i+ 9] + hc.z * w[4*i+10] + hc.w * w[4*i+11];
                acc3 += hd.x * w[4*i+12] + hd.y * w[4*i+13] + hd.z * w[4*i+14] + hd.w * w[4*i+15];
            }
        }
        float s = (acc0 + acc1) + (acc2 + acc3);
        s += __shfl_xor(s, 1);           // partner lane tid^1: full 160-dot
        if (active && half == 0) g_s[r] = s + bias;
        __syncthreads();
        if (tid < H) {
            float rg = sigmoidf_(xr + g_s[tid]);
            float z  = sigmoidf_(xz + g_s[H + tid]);
            float n  = tanhf_(xn + rg * g_s[2 * H + tid]);
            float hn = (1.0f - z) * n + z * h_s[tid];
            h_s[tid] = hn;
            out[((size_t)b * T_SEQ + tt) * 320 + (size_t)dir * H + tid] = hn;
        }
        __syncthreads();
    }
}

// ---------------- attn logits: [32768][4] = keys[tok][160] . score_w[h][160] + b ---
__global__ __launch_bounds__(256) void logits_kernel(
    const float* __restrict__ keys, const float* __restrict__ sw,
    const float* __restrict__ sb, float* __restrict__ out)
{
    int gid = blockIdx.x * 256 + threadIdx.x;
    int tok = gid >> 2, h = gid & 3;
    const float4* kr = reinterpret_cast<const float4*>(keys + (size_t)tok * H);
    const float4* wr = reinterpret_cast<const float4*>(sw + (size_t)h * H);
    float acc = 0.f;
    #pragma unroll
    for (int i = 0; i < H / 4; ++i) {
        float4 a = kr[i], w4 = wr[i];
        acc += a.x * w4.x + a.y * w4.y + a.z * w4.z + a.w * w4.w;
    }
    out[gid] = acc + sb[h];
}

// ---------------- epilogue: motion + softmax + pool + proj + LN + L2, 1 block/batch --
__global__ __launch_bounds__(512) void final_kernel(
    const float* __restrict__ x, const float* __restrict__ logits,
    const float* __restrict__ seq, const float* __restrict__ proj_w,
    const float* __restrict__ proj_b, const float* __restrict__ ln_g,
    const float* __restrict__ ln_b, float* __restrict__ out)
{
    int b   = blockIdx.x;
    int tid = threadIdx.x;
    __shared__ float ms[T_SEQ];
    __shared__ float ss[T_SEQ];
    __shared__ __align__(16) float pooled[320];
    __shared__ float red[8];

    // Phase A: motion[t] = ||x[t]-x[t-1]||, m[0]=m[1]; standardize (ddof=1)
    {
        float m = 0.f;
        if (tid >= 1) {
            const float4* xc = reinterpret_cast<const float4*>(x + ((size_t)b * T_SEQ + tid) * DIN);
            const float4* xp = reinterpret_cast<const float4*>(x + ((size_t)b * T_SEQ + tid - 1) * DIN);
            float s = 0.f;
            #pragma unroll
            for (int i = 0; i < DIN / 4; ++i) {
                float4 a = xc[i], p = xp[i];
                float dx = a.x - p.x, dy = a.y - p.y, dz = a.z - p.z, dw = a.w - p.w;
                s += dx * dx + dy * dy + dz * dz + dw * dw;
            }
            m = sqrtf(s);
        }
        ms[tid] = m;
    }
    __syncthreads();
    if (tid == 0) ms[0] = ms[1];
    __syncthreads();
    float mv   = ms[tid];
    float mean = blockReduceSum(mv, red) * (1.0f / T_SEQ);
    float var  = blockReduceSum((mv - mean) * (mv - mean), red) * (1.0f / (T_SEQ - 1));
    float mstd = (mv - mean) / (sqrtf(var) + 1e-6f);

    // Phase B: 4 softmaxes over t; s[t] = mean_h weights
    float4 lg = *reinterpret_cast<const float4*>(logits + ((size_t)b * T_SEQ + tid) * 4);
    float l[4] = {lg.x + mstd, lg.y + mstd, lg.z + mstd, lg.w + mstd};
    float ssum = 0.f;
    #pragma unroll
    for (int h = 0; h < 4; ++h) {
        float mx = blockReduceMax(l[h], red);
        float e  = __expf(l[h] - mx);
        float se = blockReduceSum(e, red);
        float wv = e / se;
        ssum += wv;
    }
    float sv = ssum * 0.25f;
    ss[tid] = sv;
    out[16384 + b * T_SEQ + tid] = sv;   // output 1: weights.mean(axis=2)
    __syncthreads();

    // Phase C: pooled[d] = sum_t seq[b,t,d] * s[t]
    if (tid < 320) {
        float acc = 0.f;
        const float* sp = seq + (size_t)b * T_SEQ * 320 + tid;
        #pragma unroll 4
        for (int t = 0; t < T_SEQ; ++t) acc += sp[(size_t)t * 320] * ss[t];
        pooled[tid] = acc;
    }
    __syncthreads();

    // Phase D: embedding = pooled . proj_w^T + b ; LN ; L2-normalize
    float e = 0.f;
    if (tid < 256) {
        const float4* pw = reinterpret_cast<const float4*>(proj_w + (size_t)tid * 320);
        const float4* pl = reinterpret_cast<const float4*>(pooled);
        float acc = 0.f;
        #pragma unroll
        for (int i = 0; i < 80; ++i) {
            float4 w4 = pw[i], p4 = pl[i];
            acc += w4.x * p4.x + w4.y * p4.y + w4.z * p4.z + w4.w * p4.w;
        }
        e = acc + proj_b[tid];
    }
    float mu = blockReduceSum(tid < 256 ? e : 0.f, red) * (1.0f / 256);
    float dv = (tid < 256) ? (e - mu) : 0.f;
    float vr = blockReduceSum(dv * dv, red) * (1.0f / 256);
    float g  = 0.f;
    if (tid < 256) g = (e - mu) * rsqrtf(vr + 1e-5f) * ln_g[tid] + ln_b[tid];
    float nrm = sqrtf(blockReduceSum(g * g, red));
    nrm = fmaxf(nrm, 1e-12f);
    if (tid < 256) out[b * 256 + tid] = g / nrm;
}

extern "C" void kernel_launch(void* const* d_in, const int* in_sizes, int n_in,
                              void* d_out, int out_size, void* d_ws, size_t ws_size,
                              hipStream_t stream) {
    const float* x       = (const float*)d_in[0];
    const float* Wih0    = (const float*)d_in[1];
    const float* Whh0    = (const float*)d_in[2];
    const float* bih0    = (const float*)d_in[3];
    const float* bhh0    = (const float*)d_in[4];
    const float* Wih1    = (const float*)d_in[5];
    const float* Whh1    = (const float*)d_in[6];
    const float* bih1    = (const float*)d_in[7];
    const float* bhh1    = (const float*)d_in[8];
    const float* key_w   = (const float*)d_in[9];
    const float* key_b   = (const float*)d_in[10];
    const float* score_w = (const float*)d_in[11];
    const float* score_b = (const float*)d_in[12];
    const float* proj_w  = (const float*)d_in[13];
    const float* proj_b  = (const float*)d_in[14];
    const float* ln_g    = (const float*)d_in[15];
    const float* ln_b    = (const float*)d_in[16];

    float* ws    = (float*)d_ws;
    float* xwbuf = ws;                        // 32768*960  = 31457280 (reused for xw1)
    float* h1    = ws + 31457280;             // 32768*320  = 10485760
    float* seq   = h1 + 10485760;             // 32768*320  = 10485760
    float* keys  = seq + 10485760;             // 32768*160  =  5242880
    float* lgts  = keys + 5242880;            // 32768*4    =   131072
    float* outf  = (float*)d_out;

    const int M = BATCH * T_SEQ;              // 32768

    gemm_bias_kernel<<<dim3(M / 64, 15), 256, 0, stream>>>(x,   Wih0, bih0, xwbuf, M, 960, 128, 0);
    gru_kernel<<<128, 1024, 0, stream>>>(xwbuf, Whh0, bhh0, h1);
    gemm_bias_kernel<<<dim3(M / 64, 15), 256, 0, stream>>>(h1,  Wih1, bih1, xwbuf, M, 960, 320, 0);
    gru_kernel<<<128, 1024, 0, stream>>>(xwbuf, Whh1, bhh1, seq);
    gemm_bias_kernel<<<dim3(M / 64, 3),  256, 0, stream>>>(seq, key_w, key_b, keys, M, 160, 320, 1);
    logits_kernel<<<512, 256, 0, stream>>>(keys, score_w, score_b, lgts);
    final_kernel<<<64, 512, 0, stream>>>(x, lgts, seq, proj_w, proj_b, ln_g, ln_b, outf);
}